// Round 14
// baseline (54.627 us; speedup 1.0000x reference)
//
#include <hip/hip_runtime.h>
#include <math.h>

// NMSLoss4: B=8, N=2048, G=64. Key-sorted (desc) space: every killer of e has
// index < e, so an ordered blocked Gauss-Seidel sweep with distributed column
// folding gives the exact sequential-NMS fixed point. Round 13: the per-step
// __syncthreads (which compiler-drains vmcnt(0) — flushing the column
// prefetch ring every step) is replaced by lgkmcnt(0) + RAW s_barrier +
// sched_barrier(0): global prefetch loads stay in flight across the barrier
// (T4 counted-wait pattern). adj is read-only in this kernel => race-free.

#define B_IMG 8
#define NN 2048
#define GG 64
#define MIN_H 50.0f
#define EPSF 1e-6f
#define TILE 256
#define NTILE 8
#define NPAIRT 36            // triangular 256x256 tile pairs
#define CSLICE 64
#define ADJ_U64 33792        // sum over words W: 64*(W+1), W=0..31

// per-image ws layout (bytes) — all per-element arrays in ORIGINAL order
#define OFF_BOXO  0          // float4[2048]                 32768
#define OFF_GTPIO 32768      // f32[2048]                     8192
#define OFF_PULLO 40960      // f32[2048]                     8192
#define OFF_AGTIO 49152      // s8[2048]                      2048
#define OFF_NPOSP 51200      // u32[8] per-chunk counts (+pad)
#define OFF_RANKP 51456      // u16[8][2048]                 32768
#define OFF_ADJ   84224      // u64[33792] triangular (rank space) 270336
#define IMG_STRIDE 354560

__device__ __forceinline__ float iou_pair(
    float ax1, float ay1, float ax2, float ay2,
    float bx1, float by1, float bx2, float by2) {
  float area_a = (ax2 - ax1) * (ay2 - ay1);
  float area_b = (bx2 - bx1) * (by2 - by1);
  float lx = fmaxf(ax1, bx1), ly = fmaxf(ay1, by1);
  float rx = fminf(ax2, bx2), ry = fminf(ay2, by2);
  float w = fmaxf(rx - lx, 0.0f), h = fmaxf(ry - ly, 0.0f);
  float inter = w * h;
  return inter / (area_a + area_b - inter + 1e-10f);
}

__device__ __forceinline__ unsigned long long make_key(int a, float sc, int idx) {
  // higher key = earlier selection; ties -> lower orig idx (jnp.argmax).
  return (a >= 0)
      ? ((unsigned long long)__float_as_uint(sc) << 32) | (unsigned)(NN - 1 - idx)
      : 0ull;
}

// row base (u64 units) of rank-space element e in the triangular adj
__device__ __forceinline__ int adj_base(int e) {
  int W = e >> 6, l = e & 63;
  return 32 * W * (W + 1) + l * (W + 1);
}

// ------------- kernel 1: rank partials + per-elem prep + adj zero -----------
__global__ __launch_bounds__(256) void k_rank(
    const int* __restrict__ agti_all,
    const float* __restrict__ gtb_all,
    const float* __restrict__ prop_all,
    unsigned char* __restrict__ ws,
    float* __restrict__ out) {
  const int bidx = blockIdx.x;
  const int b = bidx >> 6;
  const int ec = (bidx >> 3) & 7, fc = bidx & 7;
  const int tid = threadIdx.x;
  const int* agti = agti_all + b * NN;
  const float* prop = prop_all + (size_t)b * NN * 5;
  unsigned char* W = ws + (size_t)b * IMG_STRIDE;

  if (bidx == 0 && tid == 0) { out[0] = 0.f; out[1] = 0.f; }

  // zero this image's adj (64 blocks per image cooperate)
  {
    unsigned long long* adj = (unsigned long long*)(W + OFF_ADJ);
    for (int t = ((bidx & 63) << 8) + tid; t < ADJ_U64; t += 64 * 256)
      adj[t] = 0ull;
  }

  __shared__ unsigned long long fkeys[TILE];
  __shared__ float sgt[GG * 4];
  __shared__ int cnt4[4];

  const int f0 = fc << 8;
  {
    const int f = f0 + tid;
    fkeys[tid] = make_key(agti[f], prop[f * 5 + 4], f);
  }
  if (fc == 0) sgt[tid] = gtb_all[b * GG * 4 + tid];

  const int e = (ec << 8) + tid;
  const int a = agti[e];
  const float sc = prop[e * 5 + 4];
  const unsigned long long myk = make_key(a, sc, e);
  const bool pos = a >= 0;
  {
    unsigned long long bal = __ballot(pos);
    if ((tid & 63) == 0) cnt4[tid >> 6] = __popcll(bal);
  }
  __syncthreads();

  int rank = 0;
  #pragma unroll 16
  for (int ff = 0; ff < TILE; ++ff) {
    unsigned long long kf = fkeys[ff];       // LDS broadcast
    int fi = f0 + ff;
    rank += (kf > myk || (kf == myk && fi < e)) ? 1 : 0;
  }
  ((unsigned short*)(W + OFF_RANKP))[(fc << 11) + e] = (unsigned short)rank;

  if (fc == 0) {
    // per-element prep in ORIGINAL order + chunk positive count
    float4 bx = make_float4(prop[e * 5 + 0], prop[e * 5 + 1],
                            prop[e * 5 + 2], prop[e * 5 + 3]);
    float gi = 0.f, pl = 0.f;
    if (pos) {
      gi = iou_pair(sgt[a * 4 + 0], sgt[a * 4 + 1], sgt[a * 4 + 2], sgt[a * 4 + 3],
                    bx.x, bx.y, bx.z, bx.w);
      pl = -logf(fminf(0.5f + fmaxf(gi, EPSF), 1.0f)) * sc;
    }
    ((float4*)(W + OFF_BOXO))[e] = bx;
    ((float*)(W + OFF_GTPIO))[e] = gi;
    ((float*)(W + OFF_PULLO))[e] = pl;
    ((signed char*)(W + OFF_AGTIO))[e] = (signed char)a;
    if (tid == 0)
      ((unsigned*)(W + OFF_NPOSP))[ec] =
          (unsigned)(cnt4[0] + cnt4[1] + cnt4[2] + cnt4[3]);
  }
}

__device__ __forceinline__ int load_npos(const unsigned char* W) {
  const unsigned* np = (const unsigned*)(W + OFF_NPOSP);
  return (int)(np[0] + np[1] + np[2] + np[3] + np[4] + np[5] + np[6] + np[7]);
}

// ------------- kernel 2: tiled all-pairs (orig space) -> adj @ rank coords --
// Exact divide-free predicate:
// fl32(inter/denom) > 0.5f  <=>  (double)inter > (0.5+2^-25)*(double)denom
// Edge direction by rank: killer = smaller rank. Negatives rank >= npos, so
// they can only be victims (rows never read by the sweep) — no pos check.
__global__ __launch_bounds__(256) void k_pairs(unsigned char* __restrict__ ws) {
  int bx = blockIdx.x;
  const int b = bx / (NPAIRT * 4);
  int rem = bx % (NPAIRT * 4);
  int p = rem >> 2;
  const int q = rem & 3;
  int r = 0;
  #pragma unroll
  for (int t = 0; t < NTILE; ++t) {
    int wdt = NTILE - t;
    if (p < wdt) { r = t; break; }
    p -= wdt;
  }
  const int c = r + p;
  const int tid = threadIdx.x;
  unsigned char* W = ws + (size_t)b * IMG_STRIDE;
  const float4* box = (const float4*)(W + OFF_BOXO);
  const unsigned short* rp = (const unsigned short*)(W + OFF_RANKP);
  unsigned long long* adj = (unsigned long long*)(W + OFF_ADJ);

  __shared__ float4 cbox[CSLICE];
  __shared__ float carea[CSLICE];
  __shared__ unsigned short crank[CSLICE];

  const int jbase = c * TILE + q * CSLICE;
  if (tid < CSLICE) {
    int j = jbase + tid;
    float4 Bx = box[j];
    cbox[tid] = Bx;
    carea[tid] = (Bx.z - Bx.x) * (Bx.w - Bx.y);
    int rj = 0;
    #pragma unroll
    for (int fc = 0; fc < 8; ++fc) rj += rp[(fc << 11) + j];
    crank[tid] = (unsigned short)rj;
  }
  const int i = r * TILE + tid;
  const float4 A = box[i];
  const float area_a = (A.z - A.x) * (A.w - A.y);
  int ri = 0;
  #pragma unroll
  for (int fc = 0; fc < 8; ++fc) ri += rp[(fc << 11) + i];
  __syncthreads();

  const double THR = 0.5 + 0x1p-25;
  #pragma unroll 8
  for (int jj = 0; jj < CSLICE; ++jj) {
    float4 Bx = cbox[jj];
    float ab = carea[jj];
    float lx = fmaxf(A.x, Bx.x), ly = fmaxf(A.y, Bx.y);
    float rx = fminf(A.z, Bx.z), ry = fminf(A.w, Bx.w);
    float w = fmaxf(rx - lx, 0.0f), h = fmaxf(ry - ly, 0.0f);
    float inter = w * h;
    float denom = area_a + ab - inter + 1e-10f;   // ((aa+ab)-inter)+eps
    int j = jbase + jj;
    bool hit = ((double)inter > THR * (double)denom) && (j > i);
    if (hit) {
      int rj = crank[jj];
      int rv = ri > rj ? ri : rj;     // victim = larger rank
      int rk = ri > rj ? rj : ri;     // killer = smaller rank
      atomicOr(&adj[adj_base(rv) + (rk >> 6)], 1ull << (rk & 63));
    }
  }
}

// ------------- kernel 3: perm build + distributed sweep + bookkeeping -------
__global__ __launch_bounds__(512) void k_resolve(
    const float* __restrict__ gtb_all,
    unsigned char* __restrict__ ws,
    float* __restrict__ out) {
  const int b = blockIdx.x, tid = threadIdx.x;
  const int wave = tid >> 6, lane = tid & 63;
  unsigned char* W = ws + (size_t)b * IMG_STRIDE;
  const float* gtpiO = (const float*)(W + OFF_GTPIO);
  const float* pullO = (const float*)(W + OFF_PULLO);
  const signed char* agO = (const signed char*)(W + OFF_AGTIO);
  const unsigned long long* adj = (const unsigned long long*)(W + OFF_ADJ);
  const int npos = load_npos(W);

  __shared__ unsigned short perm[NN];          // sorted(rank) -> orig
  __shared__ unsigned long long selw[32];
  __shared__ int minselg[GG], bestposg[GG];
  __shared__ int s_maxsel, s_hasrem;
  __shared__ float wtp[8];

  // thread owns sorted elements e = tid + k*512, word myW[k] = k*8 + wave.
  // word w committed by wave (w&7), slot k = w>>3. Columns prefetched 4-deep
  // in a register ring cb[k][w&3] (all indices compile-time).
  const unsigned long long* rowp[4];
  unsigned long long diag[4], cb[4][4], kmask[4];
  int myW[4], kword[4];
  bool kmulti[4];
  #pragma unroll
  for (int k = 0; k < 4; ++k) {
    const int e = tid + (k << 9);
    myW[k] = (k << 3) + wave;
    rowp[k] = adj + adj_base(e);
    diag[k] = rowp[k][myW[k]];                    // intra-word killer mask
    #pragma unroll
    for (int j = 0; j < 4; ++j)
      cb[k][j] = (myW[k] > j) ? rowp[k][j] : 0ull;
    kword[k] = -1; kmask[k] = 0ull; kmulti[k] = false;
  }

  // perm: orig -> rank from partials, scatter into LDS
  {
    const unsigned short* rp = (const unsigned short*)(W + OFF_RANKP);
    #pragma unroll
    for (int k = 0; k < 4; ++k) {
      int o = tid + (k << 9);                    // original index
      int rank = 0;
      #pragma unroll
      for (int fc = 0; fc < 8; ++fc) rank += rp[(fc << 11) + o];
      perm[rank] = (unsigned short)o;
    }
  }
  if (tid == 0) { s_maxsel = -1; s_hasrem = 0; }
  if (tid < GG) { minselg[tid] = NN; bestposg[tid] = NN; }
  __syncthreads();

  // gather per-owned-sorted-element data through perm
  float mypull[4];
  int myag[4];
  #pragma unroll
  for (int k = 0; k < 4; ++k) {
    int e = tid + (k << 9);
    int o = perm[e];
    mypull[k] = pullO[o];
    myag[k] = agO[o];
  }

  // ---- blocked Gauss-Seidel sweep: one RAW barrier per word step ----
  // __syncthreads() would drain vmcnt(0) each step, flushing the prefetch
  // ring. lgkmcnt(0)+raw s_barrier keeps global loads in flight (T4); adj is
  // read-only here so un-drained loads across the barrier are race-free.
  #pragma unroll
  for (int w = 0; w < 32; ++w) {
    if (wave == (w & 7)) {
      const int k = w >> 3;                      // compile-time
      const int e = (w << 6) | lane;
      const bool alive0 = (e < npos) && (kword[k] < 0);
      const unsigned long long intra = diag[k];  // only bits < lane set
      bool alive = alive0;
      unsigned long long bal = __ballot(alive), prev;
      do {
        prev = bal;
        alive = alive0 && ((intra & bal) == 0ull);
        bal = __ballot(alive);
      } while (bal != prev);
      if (lane == 0) selw[w] = bal;
      // record intra-word SELECTED killers for has_rem bookkeeping
      unsigned long long mi = intra & bal;
      if (mi != 0ull) {
        kmulti[k] = kmulti[k] || (kword[k] >= 0);
        if (kword[k] < 0) { kword[k] = w; kmask[k] = mi; }
      }
    }
    asm volatile("s_waitcnt lgkmcnt(0)" ::: "memory");  // selw write visible
    __builtin_amdgcn_s_barrier();                       // raw: no vmcnt drain
    __builtin_amdgcn_sched_barrier(0);                  // pin selw read below
    const unsigned long long sw = selw[w];
    #pragma unroll
    for (int k = 0; k < 4; ++k) {
      if (myW[k] > w) {
        unsigned long long m = cb[k][w & 3] & sw; // fold column w
        if (m != 0ull) {
          kmulti[k] = kmulti[k] || (kword[k] >= 0);
          if (kword[k] < 0) { kword[k] = w; kmask[k] = m; }
        }
      }
      cb[k][w & 3] = (myW[k] > w + 4) ? rowp[k][w + 4] : 0ull;  // prefetch w+4
    }
  }
  __syncthreads();

  // ---- bookkeeping pass 1 ----
  float tp_part = 0.f;
  int maxsel_p = -1;
  #pragma unroll
  for (int k = 0; k < 4; ++k) {
    int e = tid + (k << 9);
    if (e < npos) {
      int g = myag[k];                           // e<npos => positive
      atomicMin(&bestposg[g], e);
      bool sel = (selw[e >> 6] >> (e & 63)) & 1ull;
      if (sel) {
        atomicMin(&minselg[g], e);
        tp_part += mypull[k];
        maxsel_p = e > maxsel_p ? e : maxsel_p;
      }
    }
  }
  #pragma unroll
  for (int off = 32; off; off >>= 1) {
    int o = __shfl_xor(maxsel_p, off, 64);
    maxsel_p = o > maxsel_p ? o : maxsel_p;
  }
  if (lane == 0) atomicMax(&s_maxsel, maxsel_p);
  __syncthreads();

  // ---- pass 2: first-of-g subtraction; has_rem from REGISTERS ----
  // killed e is active at idx_last's turn iff its selected-killer set is
  // exactly {idx_last}: single word (lw), single bit (lbit).
  const int idx_last = s_maxsel;
  if (idx_last >= 0) {
    const int lw = idx_last >> 6;
    const unsigned long long lbit = 1ull << (idx_last & 63);
    #pragma unroll
    for (int k = 0; k < 4; ++k) {
      int e = tid + (k << 9);
      if (e < npos) {
        bool sel = (selw[e >> 6] >> (e & 63)) & 1ull;
        if (sel) {
          if (e == minselg[myag[k]]) tp_part -= mypull[k];  // first of its g
        } else if (!kmulti[k] && kword[k] == lw && kmask[k] == lbit) {
          s_hasrem = 1;
        }
      }
    }
  }
  #pragma unroll
  for (int off = 32; off; off >>= 1) tp_part += __shfl_xor(tp_part, off, 64);
  if (lane == 0) wtp[wave] = tp_part;
  __syncthreads();

  // ---- push + finalize (wave 0; lane == g) ----
  if (wave == 0) {
    float mypush = 0.f;
    int mycnt2 = 0;
    int bp = bestposg[lane];
    bool seen = minselg[lane] < NN;
    if (bp < NN) {
      float h = gtb_all[b * GG * 4 + lane * 4 + 3] - gtb_all[b * GG * 4 + lane * 4 + 1];
      if (h >= MIN_H && !seen) { mypush = 1.0f - gtpiO[perm[bp]]; mycnt2 = 1; }
    }
    #pragma unroll
    for (int off = 32; off; off >>= 1) {
      mypush += __shfl_xor(mypush, off, 64);
      mycnt2 += __shfl_xor(mycnt2, off, 64);
    }
    if (lane == 0) {
      float tp = 0.f;
      #pragma unroll
      for (int w = 0; w < 8; ++w) tp += wtp[w];
      int total_sel = 0;
      for (int w = 0; w < 32; ++w) total_sel += __popcll(selw[w]);
      int distinct = 0;
      for (int g = 0; g < GG; ++g) distinct += (minselg[g] < NN) ? 1 : 0;
      int pc = total_sel - distinct;
      if (idx_last >= 0) {
        int ol = perm[idx_last];
        // last selection's pull counts only if non-first-of-g AND has_rem
        if (idx_last != minselg[agO[ol]] && !s_hasrem) tp -= pullO[ol];
      }
      float push_loss = 0.f, pull_loss = 0.f;
      if (npos > 1) {
        pull_loss = tp / ((float)pc + EPSF);
        push_loss = mypush / ((float)mycnt2 + EPSF);
      }
      atomicAdd(&out[0], push_loss * (1.0f / B_IMG));
      atomicAdd(&out[1], pull_loss * (1.0f / B_IMG));
    }
  }
}

extern "C" void kernel_launch(void* const* d_in, const int* in_sizes, int n_in,
                              void* d_out, int out_size, void* d_ws, size_t ws_size,
                              hipStream_t stream) {
  const int* agti = (const int*)d_in[1];
  const float* gtb = (const float*)d_in[2];
  const float* prop = (const float*)d_in[3];
  unsigned char* ws = (unsigned char*)d_ws;
  float* out = (float*)d_out;

  k_rank<<<B_IMG * 64, 256, 0, stream>>>(agti, gtb, prop, ws, out);
  k_pairs<<<B_IMG * NPAIRT * 4, 256, 0, stream>>>(ws);
  k_resolve<<<B_IMG, 512, 0, stream>>>(gtb, ws, out);
}

// Round 16
// 47.295 us; speedup vs baseline: 1.1550x; 1.1550x over previous
//
#include <hip/hip_runtime.h>
#include <math.h>

// NMSLoss4: B=8, N=2048, G=64. Key-sorted (desc) space: every killer of e has
// index < e, so an ordered blocked Gauss-Seidel sweep with distributed column
// folding gives the exact sequential-NMS fixed point. Round 15: adjacency
// stored LANE-MAJOR per (word, column): entry(e=(W,l), wp) at
// 32*W*(W+1) + wp*64 + l. A wave reading column wp of word W now loads 64
// CONSECUTIVE u64 (8 cache lines) instead of 64 scattered lines — the sweep
// was L1 line-fill-throughput-bound (r12/r13 latency fixes were null).

#define B_IMG 8
#define NN 2048
#define GG 64
#define MIN_H 50.0f
#define EPSF 1e-6f
#define TILE 256
#define NTILE 8
#define NPAIRT 36            // triangular 256x256 tile pairs
#define CSLICE 64
#define ADJ_U64 33792        // 64 * sum_{W=0..31}(W+1)

// per-image ws layout (bytes) — all per-element arrays in ORIGINAL order
#define OFF_BOXO  0          // float4[2048]                 32768
#define OFF_GTPIO 32768      // f32[2048]                     8192
#define OFF_PULLO 40960      // f32[2048]                     8192
#define OFF_AGTIO 49152      // s8[2048]                      2048
#define OFF_NPOSP 51200      // u32[8] per-chunk counts (+pad)
#define OFF_RANKP 51456      // u16[8][2048]                 32768
#define OFF_ADJ   84224      // u64[33792] lane-major blocks 270336
#define IMG_STRIDE 354560

__device__ __forceinline__ float iou_pair(
    float ax1, float ay1, float ax2, float ay2,
    float bx1, float by1, float bx2, float by2) {
  float area_a = (ax2 - ax1) * (ay2 - ay1);
  float area_b = (bx2 - bx1) * (by2 - by1);
  float lx = fmaxf(ax1, bx1), ly = fmaxf(ay1, by1);
  float rx = fminf(ax2, bx2), ry = fminf(ay2, by2);
  float w = fmaxf(rx - lx, 0.0f), h = fmaxf(ry - ly, 0.0f);
  float inter = w * h;
  return inter / (area_a + area_b - inter + 1e-10f);
}

__device__ __forceinline__ unsigned long long make_key(int a, float sc, int idx) {
  // higher key = earlier selection; ties -> lower orig idx (jnp.argmax).
  return (a >= 0)
      ? ((unsigned long long)__float_as_uint(sc) << 32) | (unsigned)(NN - 1 - idx)
      : 0ull;
}

// lane-major adjacency: element e=(W=e>>6, l=e&63), column word wp (<=W):
// index = 32*W*(W+1) + wp*64 + l
__device__ __forceinline__ int adj_idx(int e, int wp) {
  int W = e >> 6, l = e & 63;
  return 32 * W * (W + 1) + (wp << 6) + l;
}

// ------------- kernel 1: rank partials + per-elem prep + adj zero -----------
__global__ __launch_bounds__(256) void k_rank(
    const int* __restrict__ agti_all,
    const float* __restrict__ gtb_all,
    const float* __restrict__ prop_all,
    unsigned char* __restrict__ ws,
    float* __restrict__ out) {
  const int bidx = blockIdx.x;
  const int b = bidx >> 6;
  const int ec = (bidx >> 3) & 7, fc = bidx & 7;
  const int tid = threadIdx.x;
  const int* agti = agti_all + b * NN;
  const float* prop = prop_all + (size_t)b * NN * 5;
  unsigned char* W = ws + (size_t)b * IMG_STRIDE;

  if (bidx == 0 && tid == 0) { out[0] = 0.f; out[1] = 0.f; }

  // zero this image's adj (64 blocks per image cooperate)
  {
    unsigned long long* adj = (unsigned long long*)(W + OFF_ADJ);
    for (int t = ((bidx & 63) << 8) + tid; t < ADJ_U64; t += 64 * 256)
      adj[t] = 0ull;
  }

  __shared__ unsigned long long fkeys[TILE];
  __shared__ float sgt[GG * 4];
  __shared__ int cnt4[4];

  const int f0 = fc << 8;
  {
    const int f = f0 + tid;
    fkeys[tid] = make_key(agti[f], prop[f * 5 + 4], f);
  }
  if (fc == 0) sgt[tid] = gtb_all[b * GG * 4 + tid];

  const int e = (ec << 8) + tid;
  const int a = agti[e];
  const float sc = prop[e * 5 + 4];
  const unsigned long long myk = make_key(a, sc, e);
  const bool pos = a >= 0;
  {
    unsigned long long bal = __ballot(pos);
    if ((tid & 63) == 0) cnt4[tid >> 6] = __popcll(bal);
  }
  __syncthreads();

  int rank = 0;
  #pragma unroll 16
  for (int ff = 0; ff < TILE; ++ff) {
    unsigned long long kf = fkeys[ff];       // LDS broadcast
    int fi = f0 + ff;
    rank += (kf > myk || (kf == myk && fi < e)) ? 1 : 0;
  }
  ((unsigned short*)(W + OFF_RANKP))[(fc << 11) + e] = (unsigned short)rank;

  if (fc == 0) {
    // per-element prep in ORIGINAL order + chunk positive count
    float4 bx = make_float4(prop[e * 5 + 0], prop[e * 5 + 1],
                            prop[e * 5 + 2], prop[e * 5 + 3]);
    float gi = 0.f, pl = 0.f;
    if (pos) {
      gi = iou_pair(sgt[a * 4 + 0], sgt[a * 4 + 1], sgt[a * 4 + 2], sgt[a * 4 + 3],
                    bx.x, bx.y, bx.z, bx.w);
      pl = -logf(fminf(0.5f + fmaxf(gi, EPSF), 1.0f)) * sc;
    }
    ((float4*)(W + OFF_BOXO))[e] = bx;
    ((float*)(W + OFF_GTPIO))[e] = gi;
    ((float*)(W + OFF_PULLO))[e] = pl;
    ((signed char*)(W + OFF_AGTIO))[e] = (signed char)a;
    if (tid == 0)
      ((unsigned*)(W + OFF_NPOSP))[ec] =
          (unsigned)(cnt4[0] + cnt4[1] + cnt4[2] + cnt4[3]);
  }
}

__device__ __forceinline__ int load_npos(const unsigned char* W) {
  const unsigned* np = (const unsigned*)(W + OFF_NPOSP);
  return (int)(np[0] + np[1] + np[2] + np[3] + np[4] + np[5] + np[6] + np[7]);
}

// ------------- kernel 2: tiled all-pairs (orig space) -> adj @ rank coords --
// Exact divide-free predicate:
// fl32(inter/denom) > 0.5f  <=>  (double)inter > (0.5+2^-25)*(double)denom
// Edge direction by rank: killer = smaller rank. Negatives rank >= npos, so
// they can only be victims (rows never read by the sweep) — no pos check.
__global__ __launch_bounds__(256) void k_pairs(unsigned char* __restrict__ ws) {
  int bx = blockIdx.x;
  const int b = bx / (NPAIRT * 4);
  int rem = bx % (NPAIRT * 4);
  int p = rem >> 2;
  const int q = rem & 3;
  int r = 0;
  #pragma unroll
  for (int t = 0; t < NTILE; ++t) {
    int wdt = NTILE - t;
    if (p < wdt) { r = t; break; }
    p -= wdt;
  }
  const int c = r + p;
  const int tid = threadIdx.x;
  unsigned char* W = ws + (size_t)b * IMG_STRIDE;
  const float4* box = (const float4*)(W + OFF_BOXO);
  const unsigned short* rp = (const unsigned short*)(W + OFF_RANKP);
  unsigned long long* adj = (unsigned long long*)(W + OFF_ADJ);

  __shared__ float4 cbox[CSLICE];
  __shared__ float carea[CSLICE];
  __shared__ unsigned short crank[CSLICE];

  const int jbase = c * TILE + q * CSLICE;
  if (tid < CSLICE) {
    int j = jbase + tid;
    float4 Bx = box[j];
    cbox[tid] = Bx;
    carea[tid] = (Bx.z - Bx.x) * (Bx.w - Bx.y);
    int rj = 0;
    #pragma unroll
    for (int fc = 0; fc < 8; ++fc) rj += rp[(fc << 11) + j];
    crank[tid] = (unsigned short)rj;
  }
  const int i = r * TILE + tid;
  const float4 A = box[i];
  const float area_a = (A.z - A.x) * (A.w - A.y);
  int ri = 0;
  #pragma unroll
  for (int fc = 0; fc < 8; ++fc) ri += rp[(fc << 11) + i];
  __syncthreads();

  const double THR = 0.5 + 0x1p-25;
  #pragma unroll 8
  for (int jj = 0; jj < CSLICE; ++jj) {
    float4 Bx = cbox[jj];
    float ab = carea[jj];
    float lx = fmaxf(A.x, Bx.x), ly = fmaxf(A.y, Bx.y);
    float rx = fminf(A.z, Bx.z), ry = fminf(A.w, Bx.w);
    float w = fmaxf(rx - lx, 0.0f), h = fmaxf(ry - ly, 0.0f);
    float inter = w * h;
    float denom = area_a + ab - inter + 1e-10f;   // ((aa+ab)-inter)+eps
    int j = jbase + jj;
    bool hit = ((double)inter > THR * (double)denom) && (j > i);
    if (hit) {
      int rj = crank[jj];
      int rv = ri > rj ? ri : rj;     // victim = larger rank
      int rk = ri > rj ? rj : ri;     // killer = smaller rank
      atomicOr(&adj[adj_idx(rv, rk >> 6)], 1ull << (rk & 63));
    }
  }
}

// ------------- kernel 3: perm build + distributed sweep + bookkeeping -------
__global__ __launch_bounds__(512) void k_resolve(
    const float* __restrict__ gtb_all,
    unsigned char* __restrict__ ws,
    float* __restrict__ out) {
  const int b = blockIdx.x, tid = threadIdx.x;
  const int wave = tid >> 6, lane = tid & 63;
  unsigned char* W = ws + (size_t)b * IMG_STRIDE;
  const float* gtpiO = (const float*)(W + OFF_GTPIO);
  const float* pullO = (const float*)(W + OFF_PULLO);
  const signed char* agO = (const signed char*)(W + OFF_AGTIO);
  const unsigned long long* adj = (const unsigned long long*)(W + OFF_ADJ);
  const int npos = load_npos(W);

  __shared__ unsigned short perm[NN];          // sorted(rank) -> orig
  __shared__ unsigned long long selw[32];
  __shared__ int minselg[GG], bestposg[GG];
  __shared__ int s_maxsel, s_hasrem;
  __shared__ float wtp[8];

  // thread owns sorted elements e = tid + k*512, word myW[k] = k*8 + wave.
  // word w committed by wave (w&7), slot k = w>>3. Columns prefetched 4-deep
  // in a register ring cb[k][w&3] (all indices compile-time). Column loads
  // are COALESCED: rbase[k] + wp*64 puts 64 lanes on consecutive u64.
  const unsigned long long* rbase[4];          // adj + 32*W*(W+1) + lane
  unsigned long long diag[4], cb[4][4], kmask[4];
  int myW[4], kword[4];
  bool kmulti[4];
  #pragma unroll
  for (int k = 0; k < 4; ++k) {
    myW[k] = (k << 3) + wave;
    const int Wb = myW[k];
    rbase[k] = adj + 32 * Wb * (Wb + 1) + lane;
    diag[k] = rbase[k][Wb << 6];                  // intra-word killer mask
    #pragma unroll
    for (int j = 0; j < 4; ++j)
      cb[k][j] = (myW[k] > j) ? rbase[k][j << 6] : 0ull;
    kword[k] = -1; kmask[k] = 0ull; kmulti[k] = false;
  }

  // perm: orig -> rank from partials, scatter into LDS
  {
    const unsigned short* rp = (const unsigned short*)(W + OFF_RANKP);
    #pragma unroll
    for (int k = 0; k < 4; ++k) {
      int o = tid + (k << 9);                    // original index
      int rank = 0;
      #pragma unroll
      for (int fc = 0; fc < 8; ++fc) rank += rp[(fc << 11) + o];
      perm[rank] = (unsigned short)o;
    }
  }
  if (tid == 0) { s_maxsel = -1; s_hasrem = 0; }
  if (tid < GG) { minselg[tid] = NN; bestposg[tid] = NN; }
  __syncthreads();

  // gather per-owned-sorted-element data through perm
  float mypull[4];
  int myag[4];
  #pragma unroll
  for (int k = 0; k < 4; ++k) {
    int e = tid + (k << 9);
    int o = perm[e];
    mypull[k] = pullO[o];
    myag[k] = agO[o];
  }

  // ---- blocked Gauss-Seidel sweep: one RAW barrier per word step ----
  // (raw s_barrier avoids the vmcnt(0) drain; adj is read-only here.)
  #pragma unroll
  for (int w = 0; w < 32; ++w) {
    if (wave == (w & 7)) {
      const int k = w >> 3;                      // compile-time
      const int e = (w << 6) | lane;
      const bool alive0 = (e < npos) && (kword[k] < 0);
      const unsigned long long intra = diag[k];  // only bits < lane set
      bool alive = alive0;
      unsigned long long bal = __ballot(alive), prev;
      do {
        prev = bal;
        alive = alive0 && ((intra & bal) == 0ull);
        bal = __ballot(alive);
      } while (bal != prev);
      if (lane == 0) selw[w] = bal;
      // record intra-word SELECTED killers for has_rem bookkeeping
      unsigned long long mi = intra & bal;
      if (mi != 0ull) {
        kmulti[k] = kmulti[k] || (kword[k] >= 0);
        if (kword[k] < 0) { kword[k] = w; kmask[k] = mi; }
      }
    }
    asm volatile("s_waitcnt lgkmcnt(0)" ::: "memory");  // selw write visible
    __builtin_amdgcn_s_barrier();                       // raw: no vmcnt drain
    __builtin_amdgcn_sched_barrier(0);                  // pin selw read below
    const unsigned long long sw = selw[w];
    #pragma unroll
    for (int k = 0; k < 4; ++k) {
      if (myW[k] > w) {
        unsigned long long m = cb[k][w & 3] & sw; // fold column w
        if (m != 0ull) {
          kmulti[k] = kmulti[k] || (kword[k] >= 0);
          if (kword[k] < 0) { kword[k] = w; kmask[k] = m; }
        }
      }
      cb[k][w & 3] = (myW[k] > w + 4) ? rbase[k][(w + 4) << 6] : 0ull;
    }
  }
  __syncthreads();

  // ---- bookkeeping pass 1 ----
  float tp_part = 0.f;
  int maxsel_p = -1;
  #pragma unroll
  for (int k = 0; k < 4; ++k) {
    int e = tid + (k << 9);
    if (e < npos) {
      int g = myag[k];                           // e<npos => positive
      atomicMin(&bestposg[g], e);
      bool sel = (selw[e >> 6] >> (e & 63)) & 1ull;
      if (sel) {
        atomicMin(&minselg[g], e);
        tp_part += mypull[k];
        maxsel_p = e > maxsel_p ? e : maxsel_p;
      }
    }
  }
  #pragma unroll
  for (int off = 32; off; off >>= 1) {
    int o = __shfl_xor(maxsel_p, off, 64);
    maxsel_p = o > maxsel_p ? o : maxsel_p;
  }
  if (lane == 0) atomicMax(&s_maxsel, maxsel_p);
  __syncthreads();

  // ---- pass 2: first-of-g subtraction; has_rem from REGISTERS ----
  // killed e is active at idx_last's turn iff its selected-killer set is
  // exactly {idx_last}: single word (lw), single bit (lbit).
  const int idx_last = s_maxsel;
  if (idx_last >= 0) {
    const int lw = idx_last >> 6;
    const unsigned long long lbit = 1ull << (idx_last & 63);
    #pragma unroll
    for (int k = 0; k < 4; ++k) {
      int e = tid + (k << 9);
      if (e < npos) {
        bool sel = (selw[e >> 6] >> (e & 63)) & 1ull;
        if (sel) {
          if (e == minselg[myag[k]]) tp_part -= mypull[k];  // first of its g
        } else if (!kmulti[k] && kword[k] == lw && kmask[k] == lbit) {
          s_hasrem = 1;
        }
      }
    }
  }
  #pragma unroll
  for (int off = 32; off; off >>= 1) tp_part += __shfl_xor(tp_part, off, 64);
  if (lane == 0) wtp[wave] = tp_part;
  __syncthreads();

  // ---- push + finalize (wave 0; lane == g) ----
  if (wave == 0) {
    float mypush = 0.f;
    int mycnt2 = 0;
    int bp = bestposg[lane];
    bool seen = minselg[lane] < NN;
    if (bp < NN) {
      float h = gtb_all[b * GG * 4 + lane * 4 + 3] - gtb_all[b * GG * 4 + lane * 4 + 1];
      if (h >= MIN_H && !seen) { mypush = 1.0f - gtpiO[perm[bp]]; mycnt2 = 1; }
    }
    #pragma unroll
    for (int off = 32; off; off >>= 1) {
      mypush += __shfl_xor(mypush, off, 64);
      mycnt2 += __shfl_xor(mycnt2, off, 64);
    }
    if (lane == 0) {
      float tp = 0.f;
      #pragma unroll
      for (int w = 0; w < 8; ++w) tp += wtp[w];
      int total_sel = 0;
      for (int w = 0; w < 32; ++w) total_sel += __popcll(selw[w]);
      int distinct = 0;
      for (int g = 0; g < GG; ++g) distinct += (minselg[g] < NN) ? 1 : 0;
      int pc = total_sel - distinct;
      if (idx_last >= 0) {
        int ol = perm[idx_last];
        // last selection's pull counts only if non-first-of-g AND has_rem
        if (idx_last != minselg[agO[ol]] && !s_hasrem) tp -= pullO[ol];
      }
      float push_loss = 0.f, pull_loss = 0.f;
      if (npos > 1) {
        pull_loss = tp / ((float)pc + EPSF);
        push_loss = mypush / ((float)mycnt2 + EPSF);
      }
      atomicAdd(&out[0], push_loss * (1.0f / B_IMG));
      atomicAdd(&out[1], pull_loss * (1.0f / B_IMG));
    }
  }
}

extern "C" void kernel_launch(void* const* d_in, const int* in_sizes, int n_in,
                              void* d_out, int out_size, void* d_ws, size_t ws_size,
                              hipStream_t stream) {
  const int* agti = (const int*)d_in[1];
  const float* gtb = (const float*)d_in[2];
  const float* prop = (const float*)d_in[3];
  unsigned char* ws = (unsigned char*)d_ws;
  float* out = (float*)d_out;

  k_rank<<<B_IMG * 64, 256, 0, stream>>>(agti, gtb, prop, ws, out);
  k_pairs<<<B_IMG * NPAIRT * 4, 256, 0, stream>>>(ws);
  k_resolve<<<B_IMG, 512, 0, stream>>>(gtb, ws, out);
}